// Round 12
// baseline (3727.157 us; speedup 1.0000x reference)
//
#include <hip/hip_runtime.h>
#include <hip/hip_bf16.h>

// alphaLSTMNetwork: B=2048 sequential steps, E=16 elevators.
//   G1: pg0  = feat @ pre_Wih0^T + bih0 + bhh0            [B*16, 256]  (parallel)
//   G2: pgo  = feat @ out_Wih[:,64:]^T + bih + bhh        [B*16, 512]  (parallel)
//   K2: per-elevator 2-layer pre-LSTM + fc recurrence     (16 blocks, seq over t)
//   G4: gih  = x @ comm_Wih0^T + bih0 + bhh0              [B*16, 128]  (parallel)
//   K3: comm alpha-LSTM, 48 micro-steps, state resets/t   (1 wave per t, parallel)
//   G6: gg   = group @ out_Wih[:,:64]^T                   [B, 512]     (parallel)
//   K4: per-elevator out-LSTM recurrence                  (16 blocks, seq over t)
//   K5: heads (tar/dir softmax)                           (parallel)
// R12 = R9 (best, 2999us) + vmem-free compute waves. R10/R11 falsified the
// drain-batching and LDS-read-count models; the surviving invariant is that
// every compute wave carries global ops whose vmcnt(0) drain at __syncthreads
// sits on the critical path. Fix: loader-wave + LDS rings.
//  - k2: wave 8 (fc, slack-rich) stages pg0[n+8] into a 16-slot ring; A-waves
//    ds_read it. A/B waves have ZERO vmem.
//  - k4: 9th pure loader wave stages pgo+gg rings and flushes an LDS noh ring
//    (8-step lag). Consumer waves have ZERO vmem.
// Ring discipline: slot t&15 staged at t-8 (>=8 barriers before use); noh slot
// flushed at t+8, reused at t+16.

#define E_ 16
#define F_ 128

typedef int i4 __attribute__((ext_vector_type(4)));
typedef _Float16 hf;
typedef hf hf2 __attribute__((ext_vector_type(2)));

__device__ __forceinline__ float sigf(float x) { return 1.0f / (1.0f + __expf(-x)); }
__device__ __forceinline__ float tanhf_(float x) {
  float e = __expf(2.0f * x);
  return 1.0f - 2.0f / (e + 1.0f);
}
__device__ __forceinline__ float lane_bcast(float v, int k) {
  return __int_as_float(__builtin_amdgcn_readlane(__float_as_int(v), k));
}
__device__ __forceinline__ float fdot2(int a, int b, float c) {
#if __has_builtin(__builtin_amdgcn_fdot2)
  return __builtin_amdgcn_fdot2(__builtin_bit_cast(hf2, a),
                                __builtin_bit_cast(hf2, b), c, false);
#else
  float d;
  asm("v_dot2_f32_f16 %0, %1, %2, %3" : "=v"(d) : "v"(a), "v"(b), "v"(c));
  return d;
#endif
}

// Canonical DPP quad_perm butterflies (full-rate VALU, no LDS pipe).
// 0xB1 = quad_perm(1,0,3,2) -> lane^1 ; 0x4E = quad_perm(2,3,0,1) -> lane^2.
__device__ __forceinline__ float dpp_xor1(float x) {
  return __int_as_float(__builtin_amdgcn_update_dpp(
      __float_as_int(x), __float_as_int(x), 0xB1, 0xF, 0xF, true));
}
__device__ __forceinline__ float dpp_xor2(float x) {
  return __int_as_float(__builtin_amdgcn_update_dpp(
      __float_as_int(x), __float_as_int(x), 0x4E, 0xF, 0xF, true));
}

// ---------------------------------------------------------------------------
// fp32 -> fp16 weight conversion (one-time per call, tiny)
// ---------------------------------------------------------------------------
__global__ void f2h_kernel(const float* __restrict__ src, hf* __restrict__ dst, int n) {
  int i = blockIdx.x * 256 + threadIdx.x;
  if (i < n) dst[i] = (hf)src[i];
}

// ---------------------------------------------------------------------------
// Generic skinny GEMM: C[m,n] = sum_k A[m,k]*W[n, co+k] (+b1[n]+b2[n])
// ---------------------------------------------------------------------------
__global__ __launch_bounds__(256) void gemm_k(
    const float* __restrict__ A, int lda,
    const float* __restrict__ W, int ldw, int co,
    const float* __restrict__ b1, const float* __restrict__ b2,
    float* __restrict__ C, int N, int K) {
  __shared__ float As[64 * 65];
  __shared__ float Ws[128 * 65];
  const int tid = threadIdx.x;
  const int m0 = blockIdx.x * 64;
  const int n0 = blockIdx.y * 128;
  const int rr = tid >> 4;
  const int c4 = (tid & 15) << 2;
  const int tm = tid >> 4;
  const int tn = tid & 15;

  float acc[4][8];
#pragma unroll
  for (int i = 0; i < 4; ++i)
#pragma unroll
    for (int j = 0; j < 8; ++j) acc[i][j] = 0.0f;

  for (int kk = 0; kk < K; kk += 64) {
#pragma unroll
    for (int p = 0; p < 4; ++p) {
      const int r = rr + p * 16;
      const float4 v = *(const float4*)(A + (size_t)(m0 + r) * lda + kk + c4);
      float* dst = &As[r * 65 + c4];
      dst[0] = v.x; dst[1] = v.y; dst[2] = v.z; dst[3] = v.w;
    }
#pragma unroll
    for (int p = 0; p < 8; ++p) {
      const int n = rr + p * 16;
      const float4 v = *(const float4*)(W + (size_t)(n0 + n) * ldw + co + kk + c4);
      float* dst = &Ws[n * 65 + c4];
      dst[0] = v.x; dst[1] = v.y; dst[2] = v.z; dst[3] = v.w;
    }
    __syncthreads();
#pragma unroll 4
    for (int k = 0; k < 64; ++k) {
      float a[4], wv[8];
#pragma unroll
      for (int i = 0; i < 4; ++i) a[i] = As[(tm * 4 + i) * 65 + k];
#pragma unroll
      for (int j = 0; j < 8; ++j) wv[j] = Ws[(tn * 8 + j) * 65 + k];
#pragma unroll
      for (int i = 0; i < 4; ++i)
#pragma unroll
        for (int j = 0; j < 8; ++j) acc[i][j] += a[i] * wv[j];
    }
    __syncthreads();
  }
#pragma unroll
  for (int i = 0; i < 4; ++i) {
    const int m = m0 + tm * 4 + i;
#pragma unroll
    for (int j = 0; j < 8; ++j) {
      const int n = n0 + tn * 8 + j;
      float v = acc[i][j];
      if (b1) v += b1[n];
      if (b2) v += b2[n];
      C[(size_t)m * N + n] = v;
    }
  }
}

// ---------------------------------------------------------------------------
// K2: per-elevator pre-LSTM (2 layers) + fc. 16 blocks x 576 threads (9 waves).
// Waves 0-3 (A): L0 step n — pg read from LDS ring, ZERO vmem.
// Waves 4-7 (B): L1 step n-1 — ZERO vmem.
// Wave 8 (C): fc step n-2 (direct xout store) + stages pg0[n+8] into ring.
// QUAD layout: lane cls=l&3 owns gate cls of elem j=wg*16+(l>>2); DPP gather.
// ---------------------------------------------------------------------------
__global__ __launch_bounds__(576) void k2_pre(
    const float* __restrict__ pg0, const float* __restrict__ preh,
    const float* __restrict__ prec,
    const hf* __restrict__ hWhh0, const hf* __restrict__ hWih1,
    const hf* __restrict__ hWhh1, const hf* __restrict__ hfcW,
    const float* __restrict__ bih1, const float* __restrict__ bhh1,
    const float* __restrict__ fcb, float* __restrict__ xout, int B) {
  const int e = blockIdx.x, tid = threadIdx.x;
  const int wv = tid >> 6, l = tid & 63;
  const int cls = l & 3;
  __shared__ __align__(16) hf h0s[2][64];
  __shared__ __align__(16) hf h1s[2][64];
  __shared__ float pgr[16][256];      // pg0 ring, slot t&15

  int wa[32], wb[32];
  float bias = 0.f, c = 0.f;
  int j = 0, r = 0;

  if (wv < 4) {                       // group A: L0
    j = wv * 16 + (l >> 2);
    r = cls * 64 + j;
    const i4* p0 = (const i4*)(hWhh0 + r * 64);
#pragma unroll
    for (int i = 0; i < 8; ++i) {
      i4 a = p0[i]; wa[4*i]=a.x; wa[4*i+1]=a.y; wa[4*i+2]=a.z; wa[4*i+3]=a.w;
    }
    if (cls == 1) { c = prec[e * 128 + j]; h0s[1][j] = (hf)preh[e * 128 + j]; }
  } else if (wv < 8) {                // group B: L1
    j = (wv - 4) * 16 + (l >> 2);
    r = cls * 64 + j;
    const i4* p1 = (const i4*)(hWih1 + r * 64);
    const i4* p2 = (const i4*)(hWhh1 + r * 64);
#pragma unroll
    for (int i = 0; i < 8; ++i) {
      i4 a = p1[i]; wa[4*i]=a.x; wa[4*i+1]=a.y; wa[4*i+2]=a.z; wa[4*i+3]=a.w;
      i4 b = p2[i]; wb[4*i]=b.x; wb[4*i+1]=b.y; wb[4*i+2]=b.z; wb[4*i+3]=b.w;
    }
    bias = bih1[r] + bhh1[r];
    if (cls == 1) { c = prec[e * 128 + 64 + j]; h1s[1][j] = (hf)preh[e * 128 + 64 + j]; }
  } else {                            // group C: fc + loader
    j = l;
    const i4* pf = (const i4*)(hfcW + l * 64);
#pragma unroll
    for (int i = 0; i < 8; ++i) {
      i4 a = pf[i]; wa[4*i]=a.x; wa[4*i+1]=a.y; wa[4*i+2]=a.z; wa[4*i+3]=a.w;
    }
    bias = fcb[l];
  }
  // prologue: stage pg0 steps 0..7 cooperatively (all 576 threads)
  for (int idx = tid; idx < 8 * 256; idx += 576) {
    const int t = idx >> 8, rr_ = idx & 255;
    pgr[t][rr_] = (t < B) ? pg0[(size_t)e * 256 + (size_t)t * 4096 + rr_] : 0.f;
  }
  __syncthreads();

  auto doL0 = [&](int nn) {
    const float pgv = pgr[nn & 15][r];                    // LDS, no vmem
    const i4* hp = (const i4*)h0s[(nn + 1) & 1];          // h0(nn-1)
    float a0 = 0.f, a1 = 0.f, a2 = 0.f, a3 = 0.f;
#pragma unroll
    for (int i = 0; i < 8; ++i) {
      i4 h = hp[i];
      a0 = fdot2(wa[4*i],   h.x, a0); a1 = fdot2(wa[4*i+1], h.y, a1);
      a2 = fdot2(wa[4*i+2], h.z, a2); a3 = fdot2(wa[4*i+3], h.w, a3);
    }
    const float pre = (a0 + a1) + (a2 + a3) + pgv;        // pg0 has x-part+biases
    const float act = (cls == 2) ? tanhf_(pre) : sigf(pre);
    const float p2 = dpp_xor2(act);
    const float ig = act * p2;
    const float p1 = dpp_xor1(ig);
    if (cls == 1) {
      c = act * c + p1;
      h0s[nn & 1][j] = (hf)(p2 * tanhf_(c));
    }
  };
  auto doL1 = [&](int nn) {
    const i4* hp0 = (const i4*)h0s[(nn + 1) & 1];
    const i4* hp1 = (const i4*)h1s[nn & 1];
    float a0 = 0.f, a1 = 0.f, a2 = 0.f, a3 = 0.f;
#pragma unroll
    for (int i = 0; i < 8; ++i) {
      i4 h = hp0[i];
      a0 = fdot2(wa[4*i],   h.x, a0); a1 = fdot2(wa[4*i+1], h.y, a1);
      a2 = fdot2(wa[4*i+2], h.z, a2); a3 = fdot2(wa[4*i+3], h.w, a3);
    }
#pragma unroll
    for (int i = 0; i < 8; ++i) {
      i4 h = hp1[i];
      a0 = fdot2(wb[4*i],   h.x, a0); a1 = fdot2(wb[4*i+1], h.y, a1);
      a2 = fdot2(wb[4*i+2], h.z, a2); a3 = fdot2(wb[4*i+3], h.w, a3);
    }
    const float pre = (a0 + a1) + (a2 + a3) + bias;
    const float act = (cls == 2) ? tanhf_(pre) : sigf(pre);
    const float p2 = dpp_xor2(act);
    const float ig = act * p2;
    const float p1 = dpp_xor1(ig);
    if (cls == 1) {
      c = act * c + p1;
      h1s[(nn + 1) & 1][j] = (hf)(p2 * tanhf_(c));
    }
  };
  auto doFC = [&](int nn) {
    const i4* hp1 = (const i4*)h1s[nn & 1];
    float a0 = 0.f, a1 = 0.f, a2 = 0.f, a3 = 0.f;
#pragma unroll
    for (int i = 0; i < 8; ++i) {
      i4 h = hp1[i];
      a0 = fdot2(wa[4*i],   h.x, a0); a1 = fdot2(wa[4*i+1], h.y, a1);
      a2 = fdot2(wa[4*i+2], h.z, a2); a3 = fdot2(wa[4*i+3], h.w, a3);
    }
    const float xv = (a0 + a1) + (a2 + a3) + bias;
    xout[((size_t)(nn - 2) * E_ + e) * 64 + l] = (xv > 0.f) ? xv : 0.05f * xv;
  };

  for (int n = 0; n < B + 2; ++n) {
    if (wv < 4) {
      if (n < B) doL0(n);
    } else if (wv < 8) {
      if (n >= 1 && n <= B) doL1(n);
    } else {
      if (n >= 2) doFC(n);
      const int t = n + 8;                         // stage step n+8 into ring
      if (t < B) {
        const float* src = pg0 + (size_t)e * 256 + (size_t)t * 4096;
        float v0 = src[l], v1 = src[64 + l], v2 = src[128 + l], v3 = src[192 + l];
        float* dst = pgr[t & 15];
        dst[l] = v0; dst[64 + l] = v1; dst[128 + l] = v2; dst[192 + l] = v3;
      }
    }
    __syncthreads();
  }
}

// ---------------------------------------------------------------------------
// K3: communication alpha-LSTM. One wave per timestep t (state resets each t).
// ---------------------------------------------------------------------------
__global__ __launch_bounds__(256) void k3_comm(
    const float* __restrict__ gih0, const float* __restrict__ Whh0,
    const float* __restrict__ Wih1, const float* __restrict__ Whh1,
    const float* __restrict__ bih1, const float* __restrict__ bhh1,
    float* __restrict__ grp, int B) {
  const int w = threadIdx.x >> 6;
  const int l = threadIdx.x & 63;
  const int t = blockIdx.x * 4 + w;

  float wh0a[32], wh0b[32], wi1a[32], wi1b[32], wh1a[32], wh1b[32];
#pragma unroll
  for (int i = 0; i < 32; ++i) {
    wh0a[i] = Whh0[l * 32 + i];         wh0b[i] = Whh0[(l + 64) * 32 + i];
    wi1a[i] = Wih1[l * 32 + i];         wi1b[i] = Wih1[(l + 64) * 32 + i];
    wh1a[i] = Whh1[l * 32 + i];         wh1b[i] = Whh1[(l + 64) * 32 + i];
  }
  const float cb1a = bih1[l] + bhh1[l];
  const float cb1b = bih1[l + 64] + bhh1[l + 64];

  float h0 = 0.0f, c0 = 0.0f, h1 = 0.0f, c1 = 0.0f;
  float al = 1.0f;
  const float* gbase = gih0 + (size_t)t * (E_ * 128);
  for (int r = 0; r < 3; ++r) {
    for (int e = 0; e < E_; ++e) {
      float ga = gbase[e * 128 + l];
      float gb = gbase[e * 128 + l + 64];
#pragma unroll
      for (int k = 0; k < 32; ++k) {
        const float hv = lane_bcast(h0, k);
        ga += wh0a[k] * hv;
        gb += wh0b[k] * hv;
      }
      {
        const float fa = __shfl_xor(ga, 32);
        const float ob = __shfl_xor(gb, 32);
        c0 = sigf(fa) * c0 + al * sigf(ga) * tanhf_(gb);
        h0 = sigf(ob) * tanhf_(c0);
      }
      float ga1 = cb1a, gb1 = cb1b;
#pragma unroll
      for (int k = 0; k < 32; ++k) {
        const float hv = lane_bcast(h0, k);
        ga1 += wi1a[k] * hv;
        gb1 += wi1b[k] * hv;
      }
#pragma unroll
      for (int k = 0; k < 32; ++k) {
        const float hv = lane_bcast(h1, k);
        ga1 += wh1a[k] * hv;
        gb1 += wh1b[k] * hv;
      }
      {
        const float fa = __shfl_xor(ga1, 32);
        const float ob = __shfl_xor(gb1, 32);
        c1 = sigf(fa) * c1 + al * sigf(ga1) * tanhf_(gb1);
        h1 = sigf(ob) * tanhf_(c1);
      }
    }
    al *= 0.333f;
  }
  if (l < 32) {
    grp[(size_t)t * 64 + l] = c0;
    grp[(size_t)t * 64 + 32 + l] = c1;
  }
}

// ---------------------------------------------------------------------------
// K4: per-elevator out-LSTM. 16 blocks x 576 threads (8 consumer + 1 loader).
// Consumers (waves 0-7): QUAD layout, elem j = wave*16+(l>>2), row r=cls*128+j;
// pgo/gg from LDS rings, noh to LDS ring — ZERO vmem.
// Loader (wave 8): stages pgo+gg[n+8] into rings; flushes noh[n-8] to global.
// ---------------------------------------------------------------------------
__global__ __launch_bounds__(576) void k4_out(
    const float* __restrict__ pgo, const float* __restrict__ gg,
    const float* __restrict__ outh, const float* __restrict__ outc,
    const hf* __restrict__ hWo, float* __restrict__ noh, int B) {
  const int e = blockIdx.x, tid = threadIdx.x;
  const int wv = tid >> 6, l = tid & 63;
  const int cls = l & 3;
  const int j = (wv < 8) ? (wv * 16 + (l >> 2)) : 0;
  const int r = cls * 128 + j;
  __shared__ __align__(16) hf hs[2][128];
  __shared__ float pgor[16][512];     // pgo ring
  __shared__ float ggr[16][512];      // gg ring
  __shared__ float nohr[16][128];     // noh out-ring (flushed with 8-step lag)

  int w[64];
  if (wv < 8) {
    const i4* pw = (const i4*)(hWo + (size_t)r * 128);
#pragma unroll
    for (int i = 0; i < 16; ++i) {
      i4 a = pw[i]; w[4*i]=a.x; w[4*i+1]=a.y; w[4*i+2]=a.z; w[4*i+3]=a.w;
    }
  }
  float c = 0.f;
  if (wv < 8 && cls == 1) { c = outc[e * 128 + j]; hs[1][j] = (hf)outh[e * 128 + j]; }
  // prologue: stage rings for steps 0..7 cooperatively (all 576 threads)
  for (int idx = tid; idx < 8 * 512; idx += 576) {
    const int t = idx >> 9, rr_ = idx & 511;
    pgor[t][rr_] = (t < B) ? pgo[(size_t)e * 512 + (size_t)t * 8192 + rr_] : 0.f;
    ggr[t][rr_]  = (t < B) ? gg[(size_t)t * 512 + rr_] : 0.f;
  }
  __syncthreads();

  auto doStep = [&](int nn) {
    const float po = pgor[nn & 15][r];
    const float gv = ggr[nn & 15][r];
    const i4* hp = (const i4*)hs[(nn + 1) & 1];       // h(nn-1)
    float a0 = 0.f, a1 = 0.f, a2 = 0.f, a3 = 0.f;
#pragma unroll
    for (int i = 0; i < 16; ++i) {
      i4 h = hp[i];
      a0 = fdot2(w[4*i],   h.x, a0); a1 = fdot2(w[4*i+1], h.y, a1);
      a2 = fdot2(w[4*i+2], h.z, a2); a3 = fdot2(w[4*i+3], h.w, a3);
    }
    const float pre = (a0 + a1) + (a2 + a3) + po + gv;   // pgo has biases
    const float act = (cls == 2) ? tanhf_(pre) : sigf(pre);
    const float p2 = dpp_xor2(act);
    const float ig = act * p2;
    const float p1 = dpp_xor1(ig);
    if (cls == 1) {
      c = act * c + p1;
      const float h = p2 * tanhf_(c);
      hs[nn & 1][j] = (hf)h;
      nohr[nn & 15][j] = h;
    }
  };

  for (int n = 0; n < B; ++n) {
    if (wv < 8) {
      doStep(n);
    } else {
      // flush noh for step n-8 (slot written at n-8, barriered since)
      if (n >= 8) {
        const int m = n - 8;
        const float v0 = nohr[m & 15][l];
        const float v1 = nohr[m & 15][64 + l];
        noh[((size_t)m * E_ + e) * 128 + l] = v0;
        noh[((size_t)m * E_ + e) * 128 + 64 + l] = v1;
      }
      // stage step n+8 into rings
      const int t = n + 8;
      if (t < B) {
        const float* ps = pgo + (size_t)e * 512 + (size_t)t * 8192;
        const float* gs = gg + (size_t)t * 512;
        float tp[8], tg[8];
#pragma unroll
        for (int i = 0; i < 8; ++i) tp[i] = ps[i * 64 + l];
#pragma unroll
        for (int i = 0; i < 8; ++i) tg[i] = gs[i * 64 + l];
        float* pd = pgor[t & 15];
        float* gd = ggr[t & 15];
#pragma unroll
        for (int i = 0; i < 8; ++i) pd[i * 64 + l] = tp[i];
#pragma unroll
        for (int i = 0; i < 8; ++i) gd[i * 64 + l] = tg[i];
      }
    }
    __syncthreads();
  }
  // tail: flush the last 8 noh slots
  if (wv == 8) {
    for (int m = (B >= 8 ? B - 8 : 0); m < B; ++m) {
      noh[((size_t)m * E_ + e) * 128 + l] = nohr[m & 15][l];
      noh[((size_t)m * E_ + e) * 128 + 64 + l] = nohr[m & 15][64 + l];
    }
  }
}

// ---------------------------------------------------------------------------
// K5: heads. tar = softmax(noh@tarW^T + tb) [64], dir = softmax(noh@dirW^T + db) [3].
// ---------------------------------------------------------------------------
__global__ __launch_bounds__(256) void k5_heads(
    const float* __restrict__ noh, const float* __restrict__ tarW,
    const float* __restrict__ tarb, const float* __restrict__ dirW,
    const float* __restrict__ dirb, float* __restrict__ out) {
  __shared__ float tw[128 * 64];
  __shared__ float tb[64];
  const int tid = threadIdx.x;
  for (int idx = tid; idx < 8192; idx += 256) {
    const int j = idx >> 7, k = idx & 127;
    tw[k * 64 + j] = tarW[idx];
  }
  if (tid < 64) tb[tid] = tarb[tid];
  __syncthreads();
  const int w = tid >> 6, l = tid & 63;
  const float db0 = dirb[0], db1 = dirb[1], db2 = dirb[2];

  for (int p = 0; p < 16; ++p) {
    const int row = blockIdx.x * 64 + p * 4 + w;
    const float na = noh[(size_t)row * 128 + l];
    const float nb = noh[(size_t)row * 128 + 64 + l];
    float acc = tb[l];
#pragma unroll
    for (int k = 0; k < 64; ++k) acc += tw[k * 64 + l] * lane_bcast(na, k);
#pragma unroll
    for (int k = 0; k < 64; ++k) acc += tw[(64 + k) * 64 + l] * lane_bcast(nb, k);
    float m = acc;
#pragma unroll
    for (int s = 32; s; s >>= 1) m = fmaxf(m, __shfl_xor(m, s));
    const float ex = __expf(acc - m);
    float sm = ex;
#pragma unroll
    for (int s = 32; s; s >>= 1) sm += __shfl_xor(sm, s);
    out[(size_t)row * 67 + l] = ex / sm;
    float d0 = dirW[l] * na + dirW[64 + l] * nb;
    float d1 = dirW[128 + l] * na + dirW[192 + l] * nb;
    float d2 = dirW[256 + l] * na + dirW[320 + l] * nb;
#pragma unroll
    for (int s = 32; s; s >>= 1) {
      d0 += __shfl_xor(d0, s);
      d1 += __shfl_xor(d1, s);
      d2 += __shfl_xor(d2, s);
    }
    d0 += db0; d1 += db1; d2 += db2;
    const float dm = fmaxf(d0, fmaxf(d1, d2));
    const float e0 = __expf(d0 - dm), e1 = __expf(d1 - dm), e2 = __expf(d2 - dm);
    const float ds = e0 + e1 + e2;
    if (l < 3) out[(size_t)row * 67 + 64 + l] = (l == 0 ? e0 : (l == 1 ? e1 : e2)) / ds;
  }
}

// ---------------------------------------------------------------------------
extern "C" void kernel_launch(void* const* d_in, const int* in_sizes, int n_in,
                              void* d_out, int out_size, void* d_ws, size_t ws_size,
                              hipStream_t stream) {
  const float* features = (const float*)d_in[0];
  const float* pre_h    = (const float*)d_in[1];
  const float* pre_c    = (const float*)d_in[2];
  const float* out_h    = (const float*)d_in[3];
  const float* out_c    = (const float*)d_in[4];
  const float* pre_Wih0 = (const float*)d_in[5];
  const float* pre_Whh0 = (const float*)d_in[6];
  const float* pre_bih0 = (const float*)d_in[7];
  const float* pre_bhh0 = (const float*)d_in[8];
  const float* pre_Wih1 = (const float*)d_in[9];
  const float* pre_Whh1 = (const float*)d_in[10];
  const float* pre_bih1 = (const float*)d_in[11];
  const float* pre_bhh1 = (const float*)d_in[12];
  const float* fc_W     = (const float*)d_in[13];
  const float* fc_b     = (const float*)d_in[14];
  const float* comm_Wih0 = (const float*)d_in[15];
  const float* comm_Whh0 = (const float*)d_in[16];
  const float* comm_bih0 = (const float*)d_in[17];
  const float* comm_bhh0 = (const float*)d_in[18];
  const float* comm_Wih1 = (const float*)d_in[19];
  const float* comm_Whh1 = (const float*)d_in[20];
  const float* comm_bih1 = (const float*)d_in[21];
  const float* comm_bhh1 = (const float*)d_in[22];
  const float* out_Wih  = (const float*)d_in[23];
  const float* out_Whh  = (const float*)d_in[24];
  const float* out_bih  = (const float*)d_in[25];
  const float* out_bhh  = (const float*)d_in[26];
  const float* tar_W    = (const float*)d_in[27];
  const float* tar_b    = (const float*)d_in[28];
  const float* dir_W    = (const float*)d_in[29];
  const float* dir_b    = (const float*)d_in[30];

  const int B = in_sizes[0] / (E_ * F_);   // 2048
  float* ws = (float*)d_ws;
  float* pg0 = ws;                                  // [B*16, 256]
  float* pgo = pg0 + (size_t)B * E_ * 256;          // [B*16, 512]
  float* xbf = pgo + (size_t)B * E_ * 512;          // [B*16, 64]
  float* gih = xbf + (size_t)B * E_ * 64;           // [B*16, 128]
  float* grp = gih + (size_t)B * E_ * 128;          // [B, 64]
  float* gg  = grp + (size_t)B * 64;                // [B, 512]
  float* noh = gg + (size_t)B * 512;                // [B*16, 128]
  hf* hWhh0 = (hf*)(noh + (size_t)B * E_ * 128);    // [256*64]
  hf* hWih1 = hWhh0 + 256 * 64;                     // [256*64]
  hf* hWhh1 = hWih1 + 256 * 64;                     // [256*64]
  hf* hfcW  = hWhh1 + 256 * 64;                     // [64*64]
  hf* hWo   = hfcW + 64 * 64;                       // [512*128]
  (void)ws_size; (void)n_in; (void)out_size;

  // W0: fp32 -> fp16 weight packs for the recurrence kernels
  f2h_kernel<<<(256 * 64 + 255) / 256, 256, 0, stream>>>(pre_Whh0, hWhh0, 256 * 64);
  f2h_kernel<<<(256 * 64 + 255) / 256, 256, 0, stream>>>(pre_Wih1, hWih1, 256 * 64);
  f2h_kernel<<<(256 * 64 + 255) / 256, 256, 0, stream>>>(pre_Whh1, hWhh1, 256 * 64);
  f2h_kernel<<<(64 * 64 + 255) / 256, 256, 0, stream>>>(fc_W, hfcW, 64 * 64);
  f2h_kernel<<<(512 * 128 + 255) / 256, 256, 0, stream>>>(out_Whh, hWo, 512 * 128);

  const int MB = B * E_ / 64;

  // G1: pre-LSTM layer0 input projection (+ both biases)
  gemm_k<<<dim3(MB, 2), 256, 0, stream>>>(features, 128, pre_Wih0, 128, 0,
                                          pre_bih0, pre_bhh0, pg0, 256, 128);
  // G2: out-LSTM feat-half input projection (+ both biases)
  gemm_k<<<dim3(MB, 4), 256, 0, stream>>>(features, 128, out_Wih, 192, 64,
                                          out_bih, out_bhh, pgo, 512, 128);
  // K2: pre recurrence (writes x)
  k2_pre<<<E_, 576, 0, stream>>>(pg0, pre_h, pre_c, hWhh0, hWih1, hWhh1, hfcW,
                                 pre_bih1, pre_bhh1, fc_b, xbf, B);
  // G4: comm layer0 input projection (+ both biases)
  gemm_k<<<dim3(MB, 1), 256, 0, stream>>>(xbf, 64, comm_Wih0, 64, 0,
                                          comm_bih0, comm_bhh0, gih, 128, 64);
  // K3: comm chains (writes group cell states)
  k3_comm<<<B / 4, 256, 0, stream>>>(gih, comm_Whh0, comm_Wih1, comm_Whh1,
                                     comm_bih1, comm_bhh1, grp, B);
  // G6: out-LSTM group-half input projection
  gemm_k<<<dim3(B / 64, 4), 256, 0, stream>>>(grp, 64, out_Wih, 192, 0,
                                              nullptr, nullptr, gg, 512, 64);
  // K4: out recurrence (writes noh)
  k4_out<<<E_, 576, 0, stream>>>(pgo, gg, out_h, out_c, hWo, noh, B);
  // K5: heads + softmax -> d_out [B,16,67]
  k5_heads<<<B * E_ / 64, 256, 0, stream>>>(noh, tar_W, tar_b, dir_W, dir_b,
                                            (float*)d_out);
}